// Round 3
// baseline (93.951 us; speedup 1.0000x reference)
//
#include <hip/hip_runtime.h>
#include <cmath>

#define NPTS 12288
#define NB   64
#define NCH  9
#define NKC  10
#define PT   256        // points per tile
#define CAP  288        // pool capacity per channel (32 + 256 worst-case tile)
#define CTHR 32         // compact threshold == dump cap
#define BIGF 1000000.0f
#define SENT 1e30f

__device__ __forceinline__ float keyf(float x, float y, float z, float m) {
    float n2 = __fadd_rn(__fadd_rn(__fmul_rn(x, x), __fmul_rn(y, y)), __fmul_rn(z, z));
    return __fmul_rn(sqrtf(n2), m);
}

// 10-round pop-min over per-lane slot arrays; emits rank r to lane r.
// Tie-break: smaller index first (matches stable top_k).
template<int NS>
__device__ __forceinline__ void popmin_rounds(float (&v)[NS], int (&ii)[NS], int lane,
                                              float &keepv, int &keepi, float &last)
{
    keepv = SENT; keepi = 0; last = SENT;
#pragma unroll
    for (int r = 0; r < NKC; ++r) {
        float m = v[0]; int mi = ii[0];
#pragma unroll
        for (int s = 1; s < NS; ++s) {
            bool t = (v[s] < m) || (v[s] == m && ii[s] < mi);
            m  = t ? v[s]  : m;
            mi = t ? ii[s] : mi;
        }
        float wm = m;
#pragma unroll
        for (int d = 32; d; d >>= 1) wm = fminf(wm, __shfl_xor(wm, d));
        unsigned long long own = __ballot(m == wm);
        int wi;
        if (__popcll(own) == 1) {
            wi = __shfl(mi, (int)(__ffsll((long long)own) - 1));
        } else {
            int c2 = (m == wm) ? mi : 0x7fffffff;
#pragma unroll
            for (int d = 32; d; d >>= 1) c2 = min(c2, __shfl_xor(c2, d));
            wi = c2;
        }
#pragma unroll
        for (int s = 0; s < NS; ++s)
            if (v[s] == wm && ii[s] == wi) v[s] = SENT;
        if (lane == r) { keepv = wm; keepi = wi; }
        last = wm;
    }
}

#define PUSH(CH, K, IDX) do {                                        \
    int sl_ = atomicAdd(&pcnt[(CH)], 1);                             \
    if (sl_ < CAP) { pv[(CH)*CAP + sl_] = (K); pi[(CH)*CAP + sl_] = (IDX); } \
} while (0)

// ---------------------------------------------------------------------------
// K1: block = (chunk s, batch b), 576 threads = 9 waves.
// Per 256-pt tile: coalesced float4 staging of raw records into LDS (kpts
// record padded 24->28 floats: conflict-free, aligned b128 readback), unit
// threads (waves 0-7: 4 kpts channels each; wave 8: cpt) compute masked keys
// in registers. Tile 0 seeds a per-channel gate T via bit-bisection over
// per-lane min-2 (provably >=10 keys < T). Later tiles: gated pushes into a
// per-channel LDS pool; pop-min compaction only when pool > 32. Dump pools.
// ---------------------------------------------------------------------------
template<int S>
__global__ __launch_bounds__(576)
void k1_gate(const float* __restrict__ kpts, const float* __restrict__ cpt,
             const float* __restrict__ seg,
             float* __restrict__ dv, int* __restrict__ di, int* __restrict__ dcnt)
{
    constexpr int P  = NPTS / S;
    constexpr int NT = P / PT;
    const int s    = blockIdx.x;
    const int b    = blockIdx.y;
    const int tid  = threadIdx.x;
    const int w    = tid >> 6;
    const int lane = tid & 63;
    const int i0   = s * P;

    __shared__ float raw [PT * 28];     // 28.0 KB kpts records padded to 28 f
    __shared__ float craw[PT * 3];      //  3.0 KB cpt raw
    __shared__ float msk [PT];          //  1.0 KB
    __shared__ float key0[NCH * PT];    //  9.0 KB tile-0 keys (seed)
    __shared__ float pv  [NCH * CAP];   // 10.1 KB
    __shared__ int   pi  [NCH * CAP];   // 10.1 KB
    __shared__ int   pcnt[NCH];
    __shared__ float Tg  [NCH];

    if (tid < NCH) { pcnt[tid] = 0; Tg[tid] = SENT; }

    float4 ra, rb, rc, rcc, rsg;
    {   // prefetch tile 0 (coalesced)
        size_t base = (size_t)b * NPTS + i0;
        const float4* gk = (const float4*)(kpts + base * 24);
        ra = gk[tid]; rb = gk[tid + 576];
        if (tid < 384) rc = gk[tid + 1152];
        else {
            const float4* gc = (const float4*)(cpt + base * 3);
            rcc = gc[tid - 384];
            if (tid < 512) {
                const float4* gs = (const float4*)(seg + base * 2);
                rsg = gs[tid - 384];
            }
        }
    }

    for (int tt = 0; tt < NT; ++tt) {
        const int ibase = i0 + tt * PT;

        // ---- store staged regs to LDS ----
        {
            int f0 = tid, f1 = tid + 576;
            *(float4*)((char*)raw + (f0 / 6) * 112 + (f0 % 6) * 16) = ra;
            *(float4*)((char*)raw + (f1 / 6) * 112 + (f1 % 6) * 16) = rb;
            if (tid < 384) {
                int f2 = tid + 1152;
                *(float4*)((char*)raw + (f2 / 6) * 112 + (f2 % 6) * 16) = rc;
            } else {
                ((float4*)craw)[tid - 384] = rcc;
                if (tid < 512) {
                    int p = 2 * (tid - 384);
                    msk[p]     = (rsg.y > rsg.x) ? 1.0f : BIGF;  // argmax==1 <=> seg1>seg0
                    msk[p + 1] = (rsg.w > rsg.z) ? 1.0f : BIGF;
                }
            }
        }
        // ---- prefetch next tile (latency hidden under compute) ----
        if (tt + 1 < NT) {
            size_t base = (size_t)b * NPTS + i0 + (tt + 1) * PT;
            const float4* gk = (const float4*)(kpts + base * 24);
            ra = gk[tid]; rb = gk[tid + 576];
            if (tid < 384) rc = gk[tid + 1152];
            else {
                const float4* gc = (const float4*)(cpt + base * 3);
                rcc = gc[tid - 384];
                if (tid < 512) {
                    const float4* gs = (const float4*)(seg + base * 2);
                    rsg = gs[tid - 384];
                }
            }
        }
        __syncthreads();   // A: raw/msk visible

        // ---- compute 4 keys per thread; tile0 -> key0, else gated push ----
        {
            float k0, k1v, k2v, k3v; int c0, p0;
            bool iscpt = (w == 8);
            if (!iscpt) {
                int u = tid, h = u >> 8, p = u & 255;       // h wave-uniform
                const float* rp = raw + p * 28 + h * 12;
                float4 A  = *(const float4*)(rp);
                float4 Bv = *(const float4*)(rp + 4);
                float4 C  = *(const float4*)(rp + 8);
                float m = msk[p];
                k0  = keyf(A.x, A.y, A.z, m);
                k1v = keyf(A.w, Bv.x, Bv.y, m);
                k2v = keyf(Bv.z, Bv.w, C.x, m);
                k3v = keyf(C.y, C.z, C.w, m);
                c0 = 4 * h; p0 = p;
            } else {
                int u = tid - 512;
                const float* rp = craw + u * 12;
                float4 A  = *(const float4*)(rp);
                float4 Bv = *(const float4*)(rp + 4);
                float4 C  = *(const float4*)(rp + 8);
                float4 M  = *(const float4*)(msk + 4 * u);
                k0  = keyf(A.x, A.y, A.z, M.x);
                k1v = keyf(A.w, Bv.x, Bv.y, M.y);
                k2v = keyf(Bv.z, Bv.w, C.x, M.z);
                k3v = keyf(C.y, C.z, C.w, M.w);
                c0 = 8; p0 = 4 * u;
            }
            if (tt == 0) {
                if (!iscpt) {
                    key0[(c0 + 0) * PT + p0] = k0;
                    key0[(c0 + 1) * PT + p0] = k1v;
                    key0[(c0 + 2) * PT + p0] = k2v;
                    key0[(c0 + 3) * PT + p0] = k3v;
                } else {
                    key0[8 * PT + p0 + 0] = k0;
                    key0[8 * PT + p0 + 1] = k1v;
                    key0[8 * PT + p0 + 2] = k2v;
                    key0[8 * PT + p0 + 3] = k3v;
                }
            } else {
                if (!iscpt) {
                    int idx = ibase + p0;
                    float T0 = Tg[c0], T1 = Tg[c0+1], T2 = Tg[c0+2], T3 = Tg[c0+3];
                    if (k0  < T0) PUSH(c0 + 0, k0,  idx);
                    if (k1v < T1) PUSH(c0 + 1, k1v, idx);
                    if (k2v < T2) PUSH(c0 + 2, k2v, idx);
                    if (k3v < T3) PUSH(c0 + 3, k3v, idx);
                } else {
                    float T8 = Tg[8]; int idx = ibase + p0;
                    if (k0  < T8) PUSH(8, k0,  idx + 0);
                    if (k1v < T8) PUSH(8, k1v, idx + 1);
                    if (k2v < T8) PUSH(8, k2v, idx + 2);
                    if (k3v < T8) PUSH(8, k3v, idx + 3);
                }
            }
        }
        __syncthreads();   // B: pushes / key0 settled

        // ---- tile 0: per-channel seed (wave w == channel w) ----
        if (tt == 0) {
            const float* kcp = key0 + w * PT + 4 * lane;
            float4 kv = *(const float4*)kcp;
            // per-lane min-2 of 4
            float m1 = fminf(kv.x, kv.y), M1 = fmaxf(kv.x, kv.y);
            float m2 = fminf(kv.z, kv.w), M2 = fmaxf(kv.z, kv.w);
            float v1 = fminf(m1, m2);
            float v2 = (m1 <= m2) ? fminf(m2, M1) : fminf(m1, M2);
            unsigned b1 = __float_as_uint(v1), b2 = __float_as_uint(v2);
            // bit-bisection: smallest T with >=10 min2-values strictly below.
            // Guarantees >=10 real keys < T, so T >= the chunk's final 10th.
            unsigned lo = 0u, hi = 0x7F800000u;
            for (int it = 0; it < 24; ++it) {
                unsigned mid = (lo + hi) >> 1;
                int cc = __popcll(__ballot(b1 < mid)) + __popcll(__ballot(b2 < mid));
                if (cc >= NKC) hi = mid; else lo = mid;
            }
            float Tw = __uint_as_float(hi);
            if (lane == 0) Tg[w] = Tw;
            int idx0 = i0 + 4 * lane;
            if (kv.x < Tw) PUSH(w, kv.x, idx0 + 0);
            if (kv.y < Tw) PUSH(w, kv.y, idx0 + 1);
            if (kv.z < Tw) PUSH(w, kv.z, idx0 + 2);
            if (kv.w < Tw) PUSH(w, kv.w, idx0 + 3);
        }
        // ---- compact pool[w] if it grew past CTHR (tightens T) ----
        {
            int n = pcnt[w]; n = n > CAP ? CAP : n;
            if (n > CTHR) {
                float v5[5]; int id5[5];
#pragma unroll
                for (int s2 = 0; s2 < 5; ++s2) {
                    int e = lane + 64 * s2;
                    bool ok = e < n;
                    v5[s2]  = ok ? pv[w * CAP + e] : SENT;
                    id5[s2] = ok ? pi[w * CAP + e] : 0x7fffffff;
                }
                float keepv, last; int keepi;
                popmin_rounds<5>(v5, id5, lane, keepv, keepi, last);
                if (lane < NKC) { pv[w * CAP + lane] = keepv; pi[w * CAP + lane] = keepi; }
                if (lane == 0) { pcnt[w] = NKC; Tg[w] = last; }
            }
        }
        __syncthreads();   // C: T/pool updates visible
    }

    // ---- dump pool (n <= 32 guaranteed by per-tile compaction) ----
    int n = pcnt[w]; n = n > CTHR ? CTHR : n;
    size_t dbase = ((((size_t)b * S + s) * NCH) + w) * CTHR;
    if (lane < n) { dv[dbase + lane] = pv[w * CAP + lane]; di[dbase + lane] = pi[w * CAP + lane]; }
    if (lane == 0) dcnt[((size_t)b * S + s) * NCH + w] = n;
}

// ---------------------------------------------------------------------------
// K2: one block per batch, wave c = channel c. Merge the S dumped pools into
// the exact sorted top-10 (pop-min, (key,idx) order = stable top_k), gather
// candidates, bit-exact sequential clustering, thread-0 3x3 Jacobi SVD.
// ---------------------------------------------------------------------------

#define JROT(P_, Q_) do {                                                      \
    float aa = G[0][P_]*G[0][P_] + G[1][P_]*G[1][P_] + G[2][P_]*G[2][P_];      \
    float bb = G[0][Q_]*G[0][Q_] + G[1][Q_]*G[1][Q_] + G[2][Q_]*G[2][Q_];      \
    float gg = G[0][P_]*G[0][Q_] + G[1][P_]*G[1][Q_] + G[2][P_]*G[2][Q_];      \
    if (fabsf(gg) > 1e-30f) {                                                  \
        float zeta = (bb - aa) / (2.0f * gg);                                  \
        float tt = copysignf(1.0f, zeta) / (fabsf(zeta) + sqrtf(1.0f + zeta*zeta)); \
        float cc = 1.0f / sqrtf(1.0f + tt * tt);                               \
        float ss = cc * tt;                                                    \
        _Pragma("unroll")                                                      \
        for (int ii = 0; ii < 3; ++ii) {                                       \
            float gp = G[ii][P_], gq = G[ii][Q_];                              \
            G[ii][P_] = cc*gp - ss*gq; G[ii][Q_] = ss*gp + cc*gq;              \
            float vp = Vv[ii][P_], vq = Vv[ii][Q_];                            \
            Vv[ii][P_] = cc*vp - ss*vq; Vv[ii][Q_] = ss*vp + cc*vq;            \
        }                                                                      \
    }                                                                          \
} while (0)

#define CSWAP(P_, Q_) do { if (s##P_ < s##Q_) {                                \
    float t_ = s##P_; s##P_ = s##Q_; s##Q_ = t_;                               \
    _Pragma("unroll")                                                          \
    for (int ii = 0; ii < 3; ++ii) {                                           \
        t_ = U[ii][P_];  U[ii][P_]  = U[ii][Q_];  U[ii][Q_]  = t_;             \
        t_ = Vv[ii][P_]; Vv[ii][P_] = Vv[ii][Q_]; Vv[ii][Q_] = t_;             \
    }                                                                          \
} } while (0)

template<int S>
__global__ __launch_bounds__(576)
void k2_cluster_svd(const float* __restrict__ pcld, const float* __restrict__ kpts,
                    const float* __restrict__ cpt,  const float* __restrict__ mesh,
                    const float* __restrict__ dv,   const int* __restrict__ di,
                    const int* __restrict__ dcnt,   float* __restrict__ out)
{
    constexpr int NSL = (S * CTHR + 63) / 64;
    const int b = blockIdx.x, tid = threadIdx.x;
    const int c = tid >> 6, lane = tid & 63;

    __shared__ float scand[NCH][NKC][3];
    __shared__ float voted[NCH][3];

    int pref[S + 1];
    pref[0] = 0;
#pragma unroll
    for (int s2 = 0; s2 < S; ++s2)
        pref[s2 + 1] = pref[s2] + dcnt[((size_t)b * S + s2) * NCH + c];
    const int n = pref[S];

    float v[NSL]; int id[NSL];
#pragma unroll
    for (int k = 0; k < NSL; ++k) {
        int e = lane + 64 * k;
        if (e < n) {
            int s2 = 0, ps = 0;
#pragma unroll
            for (int j = 1; j < S; ++j) { bool g = (e >= pref[j]); s2 = g ? j : s2; ps = g ? pref[j] : ps; }
            size_t base = (((size_t)b * S + s2) * NCH + c) * CTHR + (e - ps);
            v[k] = dv[base]; id[k] = di[base];
        } else { v[k] = SENT; id[k] = 0x7fffffff; }
    }
    float keepv, last; int keepi;
    popmin_rounds<NSL>(v, id, lane, keepv, keepi, last);

    if (lane < NKC) {
        const int i = keepi;
        const float* pp = pcld + ((size_t)b * NPTS + i) * 3;
        const float* op = (c < 8) ? (kpts + (((size_t)b * NPTS + i) * 8 + c) * 3)
                                  : (cpt  + ((size_t)b * NPTS + i) * 3);
        scand[c][lane][0] = __fadd_rn(pp[0], op[0]);
        scand[c][lane][1] = __fadd_rn(pp[1], op[1]);
        scand[c][lane][2] = __fadd_rn(pp[2], op[2]);
    }
    __syncthreads();

    // ---- 27 threads: exact sequential clustering per (channel, coord) ----
    if (tid < NCH * 3) {
        const int cc = tid / 3, d = tid % 3;
        float sum = 0.0f;
#pragma unroll
        for (int q = 0; q < NKC; ++q) sum = __fadd_rn(sum, scand[cc][q][d]);
        float mu = sum / 10.0f;
        float var = 0.0f;
#pragma unroll
        for (int q = 0; q < NKC; ++q) {
            float dq = __fsub_rn(scand[cc][q][d], mu);
            var = __fadd_rn(var, __fmul_rn(dq, dq));
        }
        float sd = sqrtf(var / 10.0f);
        float fs = 0.0f; int cnt = 0;
#pragma unroll
        for (int q = 0; q < NKC; ++q) {
            float x = scand[cc][q][d];
            if (fabsf(__fsub_rn(x, mu)) < sd) {
                fs = __fadd_rn(fs, x);
                if (x != 0.0f) cnt++;
            }
        }
        float res = fs / (float)(cnt > 0 ? cnt : 1);
        voted[cc][d] = res;
        out[768 + ((size_t)b * NCH + cc) * 3 + d] = res;  // kpts_voted
    }
    __syncthreads();

    // ---- thread 0: Kabsch via 3x3 one-sided Jacobi SVD ----
    if (tid == 0) {
        float Ax[9], Ay[9], Az[9], Bx[9], By[9], Bz[9];
#pragma unroll
        for (int n2 = 0; n2 < 9; ++n2) {
            const float* mp = mesh + ((size_t)b * 9 + n2) * 3;
            Ax[n2] = mp[0]; Ay[n2] = mp[1]; Az[n2] = mp[2];
            Bx[n2] = voted[n2][0]; By[n2] = voted[n2][1]; Bz[n2] = voted[n2][2];
        }
        float cax = 0, cay = 0, caz = 0, cbx = 0, cby = 0, cbz = 0;
#pragma unroll
        for (int n2 = 0; n2 < 9; ++n2) {
            cax += Ax[n2]; cay += Ay[n2]; caz += Az[n2];
            cbx += Bx[n2]; cby += By[n2]; cbz += Bz[n2];
        }
        cax /= 9.0f; cay /= 9.0f; caz /= 9.0f;
        cbx /= 9.0f; cby /= 9.0f; cbz /= 9.0f;

        float H[3][3] = {{0,0,0},{0,0,0},{0,0,0}};
#pragma unroll
        for (int n2 = 0; n2 < 9; ++n2) {
            float a0 = Ax[n2]-cax, a1 = Ay[n2]-cay, a2 = Az[n2]-caz;
            float b0 = Bx[n2]-cbx, b1 = By[n2]-cby, b2 = Bz[n2]-cbz;
            H[0][0]+=a0*b0; H[0][1]+=a0*b1; H[0][2]+=a0*b2;
            H[1][0]+=a1*b0; H[1][1]+=a1*b1; H[1][2]+=a1*b2;
            H[2][0]+=a2*b0; H[2][1]+=a2*b1; H[2][2]+=a2*b2;
        }

        float G[3][3], Vv[3][3];
#pragma unroll
        for (int i = 0; i < 3; ++i)
#pragma unroll
            for (int j = 0; j < 3; ++j) {
                G[i][j]  = H[i][j];
                Vv[i][j] = (i == j) ? 1.0f : 0.0f;
            }
        for (int sw = 0; sw < 12; ++sw) { JROT(0,1); JROT(0,2); JROT(1,2); }

        float s0 = sqrtf(G[0][0]*G[0][0] + G[1][0]*G[1][0] + G[2][0]*G[2][0]);
        float s1 = sqrtf(G[0][1]*G[0][1] + G[1][1]*G[1][1] + G[2][1]*G[2][1]);
        float s2 = sqrtf(G[0][2]*G[0][2] + G[1][2]*G[1][2] + G[2][2]*G[2][2]);
        float r0 = 1.0f / fmaxf(s0, 1e-30f);
        float r1 = 1.0f / fmaxf(s1, 1e-30f);
        float r2 = 1.0f / fmaxf(s2, 1e-30f);
        float U[3][3];
#pragma unroll
        for (int i = 0; i < 3; ++i) {
            U[i][0] = G[i][0] * r0; U[i][1] = G[i][1] * r1; U[i][2] = G[i][2] * r2;
        }
        CSWAP(0, 1); CSWAP(1, 2); CSWAP(0, 1);   // descending singular values

        float R0[3][3];
#pragma unroll
        for (int i = 0; i < 3; ++i)
#pragma unroll
            for (int j = 0; j < 3; ++j)
                R0[i][j] = Vv[i][0]*U[j][0] + Vv[i][1]*U[j][1] + Vv[i][2]*U[j][2];
        float det = R0[0][0]*(R0[1][1]*R0[2][2] - R0[1][2]*R0[2][1])
                  - R0[0][1]*(R0[1][0]*R0[2][2] - R0[1][2]*R0[2][0])
                  + R0[0][2]*(R0[1][0]*R0[2][1] - R0[1][1]*R0[2][0]);
        float dsgn = (det >= 0.0f) ? 1.0f : -1.0f;

        float R[3][3];
#pragma unroll
        for (int i = 0; i < 3; ++i)
#pragma unroll
            for (int j = 0; j < 3; ++j) {
                R[i][j] = Vv[i][0]*U[j][0] + Vv[i][1]*U[j][1] + dsgn*Vv[i][2]*U[j][2];
                out[(size_t)b * 9 + i * 3 + j] = R[i][j];
            }
#pragma unroll
        for (int i = 0; i < 3; ++i) {
            float ti = ((i==0)?cbx:(i==1)?cby:cbz)
                     - (R[i][0]*cax + R[i][1]*cay + R[i][2]*caz);
            out[576 + (size_t)b * 3 + i] = ti;
        }
    }
}

extern "C" void kernel_launch(void* const* d_in, const int* in_sizes, int n_in,
                              void* d_out, int out_size, void* d_ws, size_t ws_size,
                              hipStream_t stream)
{
    const float* pcld = (const float*)d_in[0];
    const float* kpts = (const float*)d_in[1];
    const float* cpt  = (const float*)d_in[2];
    const float* seg  = (const float*)d_in[3];
    const float* mesh = (const float*)d_in[4];
    float* out = (float*)d_out;

    // pick largest S in {8,4,2} whose dump fits d_ws
    int S = 8;
    while (S > 2) {
        size_t need = (size_t)NB * S * NCH * CTHR * 8ull + (size_t)NB * S * NCH * 4ull;
        if (need <= ws_size) break;
        S >>= 1;
    }
    float* dvp = (float*)d_ws;
    int*   dip = (int*)((char*)d_ws + (size_t)NB * S * NCH * CTHR * 4ull);
    int*   dcp = (int*)((char*)d_ws + (size_t)NB * S * NCH * CTHR * 8ull);

    dim3 g1(S, NB);
    if (S == 8) {
        k1_gate<8><<<g1, 576, 0, stream>>>(kpts, cpt, seg, dvp, dip, dcp);
        k2_cluster_svd<8><<<NB, 576, 0, stream>>>(pcld, kpts, cpt, mesh, dvp, dip, dcp, out);
    } else if (S == 4) {
        k1_gate<4><<<g1, 576, 0, stream>>>(kpts, cpt, seg, dvp, dip, dcp);
        k2_cluster_svd<4><<<NB, 576, 0, stream>>>(pcld, kpts, cpt, mesh, dvp, dip, dcp, out);
    } else {
        k1_gate<2><<<g1, 576, 0, stream>>>(kpts, cpt, seg, dvp, dip, dcp);
        k2_cluster_svd<2><<<NB, 576, 0, stream>>>(pcld, kpts, cpt, mesh, dvp, dip, dcp, out);
    }
}

// Round 4
// 68.781 us; speedup vs baseline: 1.3659x; 1.3659x over previous
//
#include <hip/hip_runtime.h>
#include <cmath>

#define NPTS 12288
#define NB   64
#define NCH  9
#define NKC  10
#define BIGF 1000000.0f
#define SENT 1e30f
#define CSTR 16          // cnt stride in ints (64B line padding)
#define SEEDN 576        // sample points for threshold seed

__device__ __forceinline__ float keyf(float x, float y, float z, float m) {
    float n2 = __fadd_rn(__fadd_rn(__fmul_rn(x, x), __fmul_rn(y, y)), __fmul_rn(z, z));
    return __fmul_rn(sqrtf(n2), m);
}

// ---------------------------------------------------------------------------
// K0: seed per-(b,c) gate threshold T = 10th-smallest key over the first 576
// points. One block per b, 576 threads; thread t owns point t and computes
// all 9 keys from its own registers (no transpose). Wave c then reduces
// channel c: per-lane sorted-10 insert over 9 LDS values + value-only popmin.
// T >= sample k10 >= global k10, so gate (key <= T) keeps all global top-10.
// ---------------------------------------------------------------------------
__global__ __launch_bounds__(576)
void k0_seed(const float* __restrict__ kpts, const float* __restrict__ cpt,
             const float* __restrict__ seg, float* __restrict__ T)
{
    const int b = blockIdx.x, t = threadIdx.x;
    __shared__ float keys[NCH][SEEDN];

    {
        size_t base = (size_t)b * NPTS + t;
        const float4* kp = (const float4*)(kpts + base * 24);
        float f[24];
#pragma unroll
        for (int j = 0; j < 6; ++j) {
            float4 v = kp[j];
            f[4 * j] = v.x; f[4 * j + 1] = v.y; f[4 * j + 2] = v.z; f[4 * j + 3] = v.w;
        }
        const float* cp = cpt + base * 3;
        float c0 = cp[0], c1 = cp[1], c2 = cp[2];
        float2 sg = *(const float2*)(seg + base * 2);
        float m = (sg.y > sg.x) ? 1.0f : BIGF;   // argmax==1 <=> seg1>seg0
#pragma unroll
        for (int c = 0; c < 8; ++c)
            keys[c][t] = keyf(f[3 * c], f[3 * c + 1], f[3 * c + 2], m);
        keys[8][t] = keyf(c0, c1, c2, m);
    }
    __syncthreads();

    const int w = t >> 6, lane = t & 63;
    float v[NKC];
#pragma unroll
    for (int j = 0; j < NKC; ++j) v[j] = SENT;
#pragma unroll
    for (int r = 0; r < 9; ++r) {               // lane owns 9 consecutive keys
        float x = keys[w][lane * 9 + r];
        if (x < v[NKC - 1]) {
            v[NKC - 1] = x;
#pragma unroll
            for (int q = NKC - 1; q > 0; --q)
                if (v[q] < v[q - 1]) { float tv = v[q]; v[q] = v[q - 1]; v[q - 1] = tv; }
        }
    }
    float last = SENT;
#pragma unroll
    for (int r = 0; r < NKC; ++r) {             // value-only popmin (dup-collapse safe)
        float wm = v[0];
#pragma unroll
        for (int d = 32; d; d >>= 1) wm = fminf(wm, __shfl_xor(wm, d));
        if (v[0] == wm) {
#pragma unroll
            for (int q = 0; q < NKC - 1; ++q) v[q] = v[q + 1];
            v[NKC - 1] = SENT;
        }
        last = wm;
    }
    if (lane == 0) T[b * NCH + w] = last;
}

// ---------------------------------------------------------------------------
// K1: pure gated stream. One thread = one point; 6 float4 loads put the whole
// kpts record in registers -> all 9 keys by static indexing. No LDS staging,
// no barriers in the hot path. Rare accepts push (key, idx) into global
// per-(b,c) pools via atomics.
// ---------------------------------------------------------------------------
__global__ __launch_bounds__(256)
void k1_gate(const float* __restrict__ kpts, const float* __restrict__ cpt,
             const float* __restrict__ seg,  const float* __restrict__ T,
             float* __restrict__ pv, int* __restrict__ pi, int* __restrict__ cnt,
             int CAP)
{
    const int g = blockIdx.x * 256 + threadIdx.x;     // 64*12288 threads
    const int b = g / NPTS, p = g % NPTS;             // b uniform per block
    __shared__ float Ts[NCH];
    if (threadIdx.x < NCH) Ts[threadIdx.x] = T[b * NCH + threadIdx.x];
    __syncthreads();

    size_t base = (size_t)g;
    const float4* kp = (const float4*)(kpts + base * 24);
    float f[24];
#pragma unroll
    for (int j = 0; j < 6; ++j) {
        float4 v = kp[j];
        f[4 * j] = v.x; f[4 * j + 1] = v.y; f[4 * j + 2] = v.z; f[4 * j + 3] = v.w;
    }
    const float* cp = cpt + base * 3;
    float c0 = cp[0], c1 = cp[1], c2 = cp[2];
    float2 sg = *(const float2*)(seg + base * 2);
    float m = (sg.y > sg.x) ? 1.0f : BIGF;

    float k[NCH];
#pragma unroll
    for (int c = 0; c < 8; ++c) k[c] = keyf(f[3 * c], f[3 * c + 1], f[3 * c + 2], m);
    k[8] = keyf(c0, c1, c2, m);

#pragma unroll
    for (int c = 0; c < NCH; ++c) {
        if (k[c] <= Ts[c]) {
            int ch = b * NCH + c;
            int sl = atomicAdd(&cnt[ch * CSTR], 1);
            if (sl < CAP) { pv[(size_t)ch * CAP + sl] = k[c]; pi[(size_t)ch * CAP + sl] = p; }
        }
    }
}

// ---------------------------------------------------------------------------
// K2: one block per b, 576 threads, wave c = channel c. Scan pool (or exact
// full rescan on overflow), per-lane sorted-10 insert with (key,idx) stable
// order, 10-round popmin -> exact reference top_k order. Then bit-exact
// gather/clustering (27 threads) and thread-0 3x3 Jacobi SVD (Kabsch).
// ---------------------------------------------------------------------------

#define JROT(P_, Q_) do {                                                      \
    float aa = G[0][P_]*G[0][P_] + G[1][P_]*G[1][P_] + G[2][P_]*G[2][P_];      \
    float bb = G[0][Q_]*G[0][Q_] + G[1][Q_]*G[1][Q_] + G[2][Q_]*G[2][Q_];      \
    float gg = G[0][P_]*G[0][Q_] + G[1][P_]*G[1][Q_] + G[2][P_]*G[2][Q_];      \
    if (fabsf(gg) > 1e-30f) {                                                  \
        float zeta = (bb - aa) / (2.0f * gg);                                  \
        float tt = copysignf(1.0f, zeta) / (fabsf(zeta) + sqrtf(1.0f + zeta*zeta)); \
        float cc = 1.0f / sqrtf(1.0f + tt * tt);                               \
        float ss = cc * tt;                                                    \
        _Pragma("unroll")                                                      \
        for (int ii = 0; ii < 3; ++ii) {                                       \
            float gp = G[ii][P_], gq = G[ii][Q_];                              \
            G[ii][P_] = cc*gp - ss*gq; G[ii][Q_] = ss*gp + cc*gq;              \
            float vp = Vv[ii][P_], vq = Vv[ii][Q_];                            \
            Vv[ii][P_] = cc*vp - ss*vq; Vv[ii][Q_] = ss*vp + cc*vq;            \
        }                                                                      \
    }                                                                          \
} while (0)

#define CSWAP(P_, Q_) do { if (s##P_ < s##Q_) {                                \
    float t_ = s##P_; s##P_ = s##Q_; s##Q_ = t_;                               \
    _Pragma("unroll")                                                          \
    for (int ii = 0; ii < 3; ++ii) {                                           \
        t_ = U[ii][P_];  U[ii][P_]  = U[ii][Q_];  U[ii][Q_]  = t_;             \
        t_ = Vv[ii][P_]; Vv[ii][P_] = Vv[ii][Q_]; Vv[ii][Q_] = t_;             \
    }                                                                          \
} } while (0)

__global__ __launch_bounds__(576)
void k2_final(const float* __restrict__ pcld, const float* __restrict__ kpts,
              const float* __restrict__ cpt,  const float* __restrict__ seg,
              const float* __restrict__ mesh,
              const float* __restrict__ pv,   const int* __restrict__ pi,
              const int* __restrict__ cnt,    float* __restrict__ out, int CAP)
{
    const int b = blockIdx.x, tid = threadIdx.x;
    const int c = tid >> 6, lane = tid & 63;

    __shared__ float scand[NCH][NKC][3];
    __shared__ float voted[NCH][3];

    const int ch = b * NCH + c;
    const int n_raw = cnt[ch * CSTR];

    float v[NKC]; int id[NKC];
#pragma unroll
    for (int j = 0; j < NKC; ++j) { v[j] = SENT; id[j] = 0x7fffffff; }

    if (n_raw <= CAP) {
        for (int e = lane; e < n_raw; e += 64) {
            float x = pv[(size_t)ch * CAP + e]; int xi = pi[(size_t)ch * CAP + e];
            if (x < v[NKC-1] || (x == v[NKC-1] && xi < id[NKC-1])) {
                v[NKC-1] = x; id[NKC-1] = xi;
#pragma unroll
                for (int q = NKC - 1; q > 0; --q) {
                    if (v[q] < v[q-1] || (v[q] == v[q-1] && id[q] < id[q-1])) {
                        float tv = v[q]; v[q] = v[q-1]; v[q-1] = tv;
                        int   ti = id[q]; id[q] = id[q-1]; id[q-1] = ti;
                    }
                }
            }
        }
    } else {
        // exact fallback: full rescan of this channel (statistically never)
        for (int i = lane; i < NPTS; i += 64) {
            size_t base = (size_t)b * NPTS + i;
            float2 sg = *(const float2*)(seg + base * 2);
            float m = (sg.y > sg.x) ? 1.0f : BIGF;
            const float* op = (c < 8) ? (kpts + (base * 8 + c) * 3) : (cpt + base * 3);
            float x = keyf(op[0], op[1], op[2], m);
            if (x < v[NKC-1]) {
                v[NKC-1] = x; id[NKC-1] = i;
#pragma unroll
                for (int q = NKC - 1; q > 0; --q) {
                    if (v[q] < v[q-1] || (v[q] == v[q-1] && id[q] < id[q-1])) {
                        float tv = v[q]; v[q] = v[q-1]; v[q-1] = tv;
                        int   ti = id[q]; id[q] = id[q-1]; id[q-1] = ti;
                    }
                }
            }
        }
    }

    // 10-round popmin across wave; lane r keeps rank r ((key,idx) stable order)
    float keepv = SENT; int keepi = 0;
#pragma unroll
    for (int r = 0; r < NKC; ++r) {
        float m = v[0]; int mi = id[0];
        float wm = m;
#pragma unroll
        for (int d = 32; d; d >>= 1) wm = fminf(wm, __shfl_xor(wm, d));
        int c2 = (m == wm) ? mi : 0x7fffffff;
#pragma unroll
        for (int d = 32; d; d >>= 1) c2 = min(c2, __shfl_xor(c2, d));
        if (m == wm && mi == c2) {
#pragma unroll
            for (int q = 0; q < NKC - 1; ++q) { v[q] = v[q + 1]; id[q] = id[q + 1]; }
            v[NKC - 1] = SENT; id[NKC - 1] = 0x7fffffff;
        }
        if (lane == r) { keepv = wm; keepi = c2; }
    }

    if (lane < NKC) {
        const int i = keepi;
        size_t base = (size_t)b * NPTS + i;
        const float* pp = pcld + base * 3;
        const float* op = (c < 8) ? (kpts + (base * 8 + c) * 3) : (cpt + base * 3);
        scand[c][lane][0] = __fadd_rn(pp[0], op[0]);
        scand[c][lane][1] = __fadd_rn(pp[1], op[1]);
        scand[c][lane][2] = __fadd_rn(pp[2], op[2]);
    }
    __syncthreads();

    // ---- 27 threads: exact sequential clustering per (channel, coord) ----
    if (tid < NCH * 3) {
        const int cc = tid / 3, d = tid % 3;
        float sum = 0.0f;
#pragma unroll
        for (int q = 0; q < NKC; ++q) sum = __fadd_rn(sum, scand[cc][q][d]);
        float mu = sum / 10.0f;
        float var = 0.0f;
#pragma unroll
        for (int q = 0; q < NKC; ++q) {
            float dq = __fsub_rn(scand[cc][q][d], mu);
            var = __fadd_rn(var, __fmul_rn(dq, dq));
        }
        float sd = sqrtf(var / 10.0f);
        float fs = 0.0f; int cntk = 0;
#pragma unroll
        for (int q = 0; q < NKC; ++q) {
            float x = scand[cc][q][d];
            if (fabsf(__fsub_rn(x, mu)) < sd) {
                fs = __fadd_rn(fs, x);
                if (x != 0.0f) cntk++;
            }
        }
        float res = fs / (float)(cntk > 0 ? cntk : 1);
        voted[cc][d] = res;
        out[768 + ((size_t)b * NCH + cc) * 3 + d] = res;  // kpts_voted
    }
    __syncthreads();

    // ---- thread 0: Kabsch via 3x3 one-sided Jacobi SVD ----
    if (tid == 0) {
        float Ax[9], Ay[9], Az[9], Bx[9], By[9], Bz[9];
#pragma unroll
        for (int n2 = 0; n2 < 9; ++n2) {
            const float* mp = mesh + ((size_t)b * 9 + n2) * 3;
            Ax[n2] = mp[0]; Ay[n2] = mp[1]; Az[n2] = mp[2];
            Bx[n2] = voted[n2][0]; By[n2] = voted[n2][1]; Bz[n2] = voted[n2][2];
        }
        float cax = 0, cay = 0, caz = 0, cbx = 0, cby = 0, cbz = 0;
#pragma unroll
        for (int n2 = 0; n2 < 9; ++n2) {
            cax += Ax[n2]; cay += Ay[n2]; caz += Az[n2];
            cbx += Bx[n2]; cby += By[n2]; cbz += Bz[n2];
        }
        cax /= 9.0f; cay /= 9.0f; caz /= 9.0f;
        cbx /= 9.0f; cby /= 9.0f; cbz /= 9.0f;

        float H[3][3] = {{0,0,0},{0,0,0},{0,0,0}};
#pragma unroll
        for (int n2 = 0; n2 < 9; ++n2) {
            float a0 = Ax[n2]-cax, a1 = Ay[n2]-cay, a2 = Az[n2]-caz;
            float b0 = Bx[n2]-cbx, b1 = By[n2]-cby, b2 = Bz[n2]-cbz;
            H[0][0]+=a0*b0; H[0][1]+=a0*b1; H[0][2]+=a0*b2;
            H[1][0]+=a1*b0; H[1][1]+=a1*b1; H[1][2]+=a1*b2;
            H[2][0]+=a2*b0; H[2][1]+=a2*b1; H[2][2]+=a2*b2;
        }

        float G[3][3], Vv[3][3];
#pragma unroll
        for (int i = 0; i < 3; ++i)
#pragma unroll
            for (int j = 0; j < 3; ++j) {
                G[i][j]  = H[i][j];
                Vv[i][j] = (i == j) ? 1.0f : 0.0f;
            }
        for (int sw = 0; sw < 12; ++sw) { JROT(0,1); JROT(0,2); JROT(1,2); }

        float s0 = sqrtf(G[0][0]*G[0][0] + G[1][0]*G[1][0] + G[2][0]*G[2][0]);
        float s1 = sqrtf(G[0][1]*G[0][1] + G[1][1]*G[1][1] + G[2][1]*G[2][1]);
        float s2 = sqrtf(G[0][2]*G[0][2] + G[1][2]*G[1][2] + G[2][2]*G[2][2]);
        float r0 = 1.0f / fmaxf(s0, 1e-30f);
        float r1 = 1.0f / fmaxf(s1, 1e-30f);
        float r2 = 1.0f / fmaxf(s2, 1e-30f);
        float U[3][3];
#pragma unroll
        for (int i = 0; i < 3; ++i) {
            U[i][0] = G[i][0] * r0; U[i][1] = G[i][1] * r1; U[i][2] = G[i][2] * r2;
        }
        CSWAP(0, 1); CSWAP(1, 2); CSWAP(0, 1);   // descending singular values

        float R0[3][3];
#pragma unroll
        for (int i = 0; i < 3; ++i)
#pragma unroll
            for (int j = 0; j < 3; ++j)
                R0[i][j] = Vv[i][0]*U[j][0] + Vv[i][1]*U[j][1] + Vv[i][2]*U[j][2];
        float det = R0[0][0]*(R0[1][1]*R0[2][2] - R0[1][2]*R0[2][1])
                  - R0[0][1]*(R0[1][0]*R0[2][2] - R0[1][2]*R0[2][0])
                  + R0[0][2]*(R0[1][0]*R0[2][1] - R0[1][1]*R0[2][0]);
        float dsgn = (det >= 0.0f) ? 1.0f : -1.0f;

        float R[3][3];
#pragma unroll
        for (int i = 0; i < 3; ++i)
#pragma unroll
            for (int j = 0; j < 3; ++j) {
                R[i][j] = Vv[i][0]*U[j][0] + Vv[i][1]*U[j][1] + dsgn*Vv[i][2]*U[j][2];
                out[(size_t)b * 9 + i * 3 + j] = R[i][j];
            }
#pragma unroll
        for (int i = 0; i < 3; ++i) {
            float ti = ((i==0)?cbx:(i==1)?cby:cbz)
                     - (R[i][0]*cax + R[i][1]*cay + R[i][2]*caz);
            out[576 + (size_t)b * 3 + i] = ti;
        }
    }
}

extern "C" void kernel_launch(void* const* d_in, const int* in_sizes, int n_in,
                              void* d_out, int out_size, void* d_ws, size_t ws_size,
                              hipStream_t stream)
{
    const float* pcld = (const float*)d_in[0];
    const float* kpts = (const float*)d_in[1];
    const float* cpt  = (const float*)d_in[2];
    const float* seg  = (const float*)d_in[3];
    const float* mesh = (const float*)d_in[4];
    float* out = (float*)d_out;

    // workspace layout: T[576] f | cnt[576*CSTR] i | pv[576*CAP] f | pi[576*CAP] i
    const size_t tBytes   = (size_t)NB * NCH * sizeof(float);           // 2304
    const size_t cntBytes = (size_t)NB * NCH * CSTR * sizeof(int);      // 36864
    size_t avail = (ws_size > tBytes + cntBytes) ? ws_size - tBytes - cntBytes : 0;
    int CAP = (int)(avail / ((size_t)NB * NCH * 8ull));
    if (CAP > 2048) CAP = 2048;
    if (CAP < 16)   CAP = 16;   // correctness safe via K2 rescan fallback

    float* Tp  = (float*)d_ws;
    int*   cp_ = (int*)((char*)d_ws + tBytes);
    float* pvp = (float*)((char*)d_ws + tBytes + cntBytes);
    int*   pip = (int*)((char*)pvp + (size_t)NB * NCH * CAP * sizeof(float));

    k0_seed<<<NB, 576, 0, stream>>>(kpts, cpt, seg, Tp);
    hipMemsetAsync(cp_, 0, cntBytes, stream);
    k1_gate<<<(NB * NPTS) / 256, 256, 0, stream>>>(kpts, cpt, seg, Tp, pvp, pip, cp_, CAP);
    k2_final<<<NB, 576, 0, stream>>>(pcld, kpts, cpt, seg, mesh, pvp, pip, cp_, out, CAP);
}

// Round 5
// 67.345 us; speedup vs baseline: 1.3951x; 1.0213x over previous
//
#include <hip/hip_runtime.h>
#include <cmath>

#define NPTS 12288
#define NB   64
#define NCH  9
#define NKC  10
#define BIGF 1000000.0f
#define SENT 1e30f
#define CSTR 16          // cnt stride in ints (64B line padding)
#define SEEDN 576        // sample points for threshold seed

__device__ __forceinline__ float keyf(float x, float y, float z, float m) {
    float n2 = __fadd_rn(__fadd_rn(__fmul_rn(x, x), __fmul_rn(y, y)), __fmul_rn(z, z));
    return __fmul_rn(sqrtf(n2), m);
}

// ---------------------------------------------------------------------------
// K0: seed per-(b,c) gate threshold T = 10th-smallest key over the first 576
// points; also zeroes this batch's pool counters (replaces the 43us memset
// that dominated R4's profile). One block per b, 576 threads; thread t owns
// point t and computes all 9 keys from its own registers (no transpose).
// Wave c reduces channel c. T >= sample k10 >= global k10 => gate keeps all.
// ---------------------------------------------------------------------------
__global__ __launch_bounds__(576)
void k0_seed(const float* __restrict__ kpts, const float* __restrict__ cpt,
             const float* __restrict__ seg, float* __restrict__ T,
             int* __restrict__ cnt)
{
    const int b = blockIdx.x, t = threadIdx.x;
    __shared__ float keys[NCH][SEEDN];

    if (t < NCH * CSTR) cnt[b * NCH * CSTR + t] = 0;   // zero pool counters

    {
        size_t base = (size_t)b * NPTS + t;
        const float4* kp = (const float4*)(kpts + base * 24);
        float f[24];
#pragma unroll
        for (int j = 0; j < 6; ++j) {
            float4 v = kp[j];
            f[4 * j] = v.x; f[4 * j + 1] = v.y; f[4 * j + 2] = v.z; f[4 * j + 3] = v.w;
        }
        const float* cp = cpt + base * 3;
        float c0 = cp[0], c1 = cp[1], c2 = cp[2];
        float2 sg = *(const float2*)(seg + base * 2);
        float m = (sg.y > sg.x) ? 1.0f : BIGF;   // argmax==1 <=> seg1>seg0
#pragma unroll
        for (int c = 0; c < 8; ++c)
            keys[c][t] = keyf(f[3 * c], f[3 * c + 1], f[3 * c + 2], m);
        keys[8][t] = keyf(c0, c1, c2, m);
    }
    __syncthreads();

    const int w = t >> 6, lane = t & 63;
    float v[NKC];
#pragma unroll
    for (int j = 0; j < NKC; ++j) v[j] = SENT;
#pragma unroll
    for (int r = 0; r < 9; ++r) {               // lane owns 9 consecutive keys
        float x = keys[w][lane * 9 + r];
        if (x < v[NKC - 1]) {
            v[NKC - 1] = x;
#pragma unroll
            for (int q = NKC - 1; q > 0; --q)
                if (v[q] < v[q - 1]) { float tv = v[q]; v[q] = v[q - 1]; v[q - 1] = tv; }
        }
    }
    float last = SENT;
#pragma unroll
    for (int r = 0; r < NKC; ++r) {             // value-only popmin (dup-collapse safe)
        float wm = v[0];
#pragma unroll
        for (int d = 32; d; d >>= 1) wm = fminf(wm, __shfl_xor(wm, d));
        if (v[0] == wm) {
#pragma unroll
            for (int q = 0; q < NKC - 1; ++q) v[q] = v[q + 1];
            v[NKC - 1] = SENT;
        }
        last = wm;
    }
    if (lane == 0) T[b * NCH + w] = last;
}

// ---------------------------------------------------------------------------
// K1: pure gated stream. One thread = one point; 6 float4 loads put the whole
// kpts record in registers -> all 9 keys by static indexing. No LDS staging,
// no barriers in the hot path. Rare accepts push (key, idx) into global
// per-(b,c) pools via atomics.
// ---------------------------------------------------------------------------
__global__ __launch_bounds__(256)
void k1_gate(const float* __restrict__ kpts, const float* __restrict__ cpt,
             const float* __restrict__ seg,  const float* __restrict__ T,
             float* __restrict__ pv, int* __restrict__ pi, int* __restrict__ cnt,
             int CAP)
{
    const int g = blockIdx.x * 256 + threadIdx.x;     // 64*12288 threads
    const int b = g / NPTS, p = g % NPTS;             // b uniform per block
    __shared__ float Ts[NCH];
    if (threadIdx.x < NCH) Ts[threadIdx.x] = T[b * NCH + threadIdx.x];
    __syncthreads();

    size_t base = (size_t)g;
    const float4* kp = (const float4*)(kpts + base * 24);
    float f[24];
#pragma unroll
    for (int j = 0; j < 6; ++j) {
        float4 v = kp[j];
        f[4 * j] = v.x; f[4 * j + 1] = v.y; f[4 * j + 2] = v.z; f[4 * j + 3] = v.w;
    }
    const float* cp = cpt + base * 3;
    float c0 = cp[0], c1 = cp[1], c2 = cp[2];
    float2 sg = *(const float2*)(seg + base * 2);
    float m = (sg.y > sg.x) ? 1.0f : BIGF;

    float k[NCH];
#pragma unroll
    for (int c = 0; c < 8; ++c) k[c] = keyf(f[3 * c], f[3 * c + 1], f[3 * c + 2], m);
    k[8] = keyf(c0, c1, c2, m);

#pragma unroll
    for (int c = 0; c < NCH; ++c) {
        if (k[c] <= Ts[c]) {
            int ch = b * NCH + c;
            int sl = atomicAdd(&cnt[ch * CSTR], 1);
            if (sl < CAP) { pv[(size_t)ch * CAP + sl] = k[c]; pi[(size_t)ch * CAP + sl] = p; }
        }
    }
}

// ---------------------------------------------------------------------------
// K2: one block per b, 576 threads, wave c = channel c. Scan pool (or exact
// full rescan on overflow), per-lane sorted-10 insert with (key,idx) stable
// order, 10-round popmin -> exact reference top_k order. Then bit-exact
// gather/clustering (27 threads) and thread-0 3x3 Jacobi SVD (Kabsch).
// ---------------------------------------------------------------------------

#define JROT(P_, Q_) do {                                                      \
    float aa = G[0][P_]*G[0][P_] + G[1][P_]*G[1][P_] + G[2][P_]*G[2][P_];      \
    float bb = G[0][Q_]*G[0][Q_] + G[1][Q_]*G[1][Q_] + G[2][Q_]*G[2][Q_];      \
    float gg = G[0][P_]*G[0][Q_] + G[1][P_]*G[1][Q_] + G[2][P_]*G[2][Q_];      \
    if (fabsf(gg) > 1e-30f) {                                                  \
        float zeta = (bb - aa) / (2.0f * gg);                                  \
        float tt = copysignf(1.0f, zeta) / (fabsf(zeta) + sqrtf(1.0f + zeta*zeta)); \
        float cc = 1.0f / sqrtf(1.0f + tt * tt);                               \
        float ss = cc * tt;                                                    \
        _Pragma("unroll")                                                      \
        for (int ii = 0; ii < 3; ++ii) {                                       \
            float gp = G[ii][P_], gq = G[ii][Q_];                              \
            G[ii][P_] = cc*gp - ss*gq; G[ii][Q_] = ss*gp + cc*gq;              \
            float vp = Vv[ii][P_], vq = Vv[ii][Q_];                            \
            Vv[ii][P_] = cc*vp - ss*vq; Vv[ii][Q_] = ss*vp + cc*vq;            \
        }                                                                      \
    }                                                                          \
} while (0)

#define CSWAP(P_, Q_) do { if (s##P_ < s##Q_) {                                \
    float t_ = s##P_; s##P_ = s##Q_; s##Q_ = t_;                               \
    _Pragma("unroll")                                                          \
    for (int ii = 0; ii < 3; ++ii) {                                           \
        t_ = U[ii][P_];  U[ii][P_]  = U[ii][Q_];  U[ii][Q_]  = t_;             \
        t_ = Vv[ii][P_]; Vv[ii][P_] = Vv[ii][Q_]; Vv[ii][Q_] = t_;             \
    }                                                                          \
} } while (0)

__global__ __launch_bounds__(576)
void k2_final(const float* __restrict__ pcld, const float* __restrict__ kpts,
              const float* __restrict__ cpt,  const float* __restrict__ seg,
              const float* __restrict__ mesh,
              const float* __restrict__ pv,   const int* __restrict__ pi,
              const int* __restrict__ cnt,    float* __restrict__ out, int CAP)
{
    const int b = blockIdx.x, tid = threadIdx.x;
    const int c = tid >> 6, lane = tid & 63;

    __shared__ float scand[NCH][NKC][3];
    __shared__ float voted[NCH][3];

    const int ch = b * NCH + c;
    const int n_raw = cnt[ch * CSTR];

    float v[NKC]; int id[NKC];
#pragma unroll
    for (int j = 0; j < NKC; ++j) { v[j] = SENT; id[j] = 0x7fffffff; }

    if (n_raw <= CAP) {
        for (int e = lane; e < n_raw; e += 64) {
            float x = pv[(size_t)ch * CAP + e]; int xi = pi[(size_t)ch * CAP + e];
            if (x < v[NKC-1] || (x == v[NKC-1] && xi < id[NKC-1])) {
                v[NKC-1] = x; id[NKC-1] = xi;
#pragma unroll
                for (int q = NKC - 1; q > 0; --q) {
                    if (v[q] < v[q-1] || (v[q] == v[q-1] && id[q] < id[q-1])) {
                        float tv = v[q]; v[q] = v[q-1]; v[q-1] = tv;
                        int   ti = id[q]; id[q] = id[q-1]; id[q-1] = ti;
                    }
                }
            }
        }
    } else {
        // exact fallback: full rescan of this channel (statistically never)
        for (int i = lane; i < NPTS; i += 64) {
            size_t base = (size_t)b * NPTS + i;
            float2 sg = *(const float2*)(seg + base * 2);
            float m = (sg.y > sg.x) ? 1.0f : BIGF;
            const float* op = (c < 8) ? (kpts + (base * 8 + c) * 3) : (cpt + base * 3);
            float x = keyf(op[0], op[1], op[2], m);
            if (x < v[NKC-1]) {
                v[NKC-1] = x; id[NKC-1] = i;
#pragma unroll
                for (int q = NKC - 1; q > 0; --q) {
                    if (v[q] < v[q-1] || (v[q] == v[q-1] && id[q] < id[q-1])) {
                        float tv = v[q]; v[q] = v[q-1]; v[q-1] = tv;
                        int   ti = id[q]; id[q] = id[q-1]; id[q-1] = ti;
                    }
                }
            }
        }
    }

    // 10-round popmin across wave; lane r keeps rank r ((key,idx) stable order)
    float keepv = SENT; int keepi = 0;
#pragma unroll
    for (int r = 0; r < NKC; ++r) {
        float m = v[0]; int mi = id[0];
        float wm = m;
#pragma unroll
        for (int d = 32; d; d >>= 1) wm = fminf(wm, __shfl_xor(wm, d));
        int c2 = (m == wm) ? mi : 0x7fffffff;
#pragma unroll
        for (int d = 32; d; d >>= 1) c2 = min(c2, __shfl_xor(c2, d));
        if (m == wm && mi == c2) {
#pragma unroll
            for (int q = 0; q < NKC - 1; ++q) { v[q] = v[q + 1]; id[q] = id[q + 1]; }
            v[NKC - 1] = SENT; id[NKC - 1] = 0x7fffffff;
        }
        if (lane == r) { keepv = wm; keepi = c2; }
    }

    if (lane < NKC) {
        const int i = keepi;
        size_t base = (size_t)b * NPTS + i;
        const float* pp = pcld + base * 3;
        const float* op = (c < 8) ? (kpts + (base * 8 + c) * 3) : (cpt + base * 3);
        scand[c][lane][0] = __fadd_rn(pp[0], op[0]);
        scand[c][lane][1] = __fadd_rn(pp[1], op[1]);
        scand[c][lane][2] = __fadd_rn(pp[2], op[2]);
    }
    __syncthreads();

    // ---- 27 threads: exact sequential clustering per (channel, coord) ----
    if (tid < NCH * 3) {
        const int cc = tid / 3, d = tid % 3;
        float sum = 0.0f;
#pragma unroll
        for (int q = 0; q < NKC; ++q) sum = __fadd_rn(sum, scand[cc][q][d]);
        float mu = sum / 10.0f;
        float var = 0.0f;
#pragma unroll
        for (int q = 0; q < NKC; ++q) {
            float dq = __fsub_rn(scand[cc][q][d], mu);
            var = __fadd_rn(var, __fmul_rn(dq, dq));
        }
        float sd = sqrtf(var / 10.0f);
        float fs = 0.0f; int cntk = 0;
#pragma unroll
        for (int q = 0; q < NKC; ++q) {
            float x = scand[cc][q][d];
            if (fabsf(__fsub_rn(x, mu)) < sd) {
                fs = __fadd_rn(fs, x);
                if (x != 0.0f) cntk++;
            }
        }
        float res = fs / (float)(cntk > 0 ? cntk : 1);
        voted[cc][d] = res;
        out[768 + ((size_t)b * NCH + cc) * 3 + d] = res;  // kpts_voted
    }
    __syncthreads();

    // ---- thread 0: Kabsch via 3x3 one-sided Jacobi SVD ----
    if (tid == 0) {
        float Ax[9], Ay[9], Az[9], Bx[9], By[9], Bz[9];
#pragma unroll
        for (int n2 = 0; n2 < 9; ++n2) {
            const float* mp = mesh + ((size_t)b * 9 + n2) * 3;
            Ax[n2] = mp[0]; Ay[n2] = mp[1]; Az[n2] = mp[2];
            Bx[n2] = voted[n2][0]; By[n2] = voted[n2][1]; Bz[n2] = voted[n2][2];
        }
        float cax = 0, cay = 0, caz = 0, cbx = 0, cby = 0, cbz = 0;
#pragma unroll
        for (int n2 = 0; n2 < 9; ++n2) {
            cax += Ax[n2]; cay += Ay[n2]; caz += Az[n2];
            cbx += Bx[n2]; cby += By[n2]; cbz += Bz[n2];
        }
        cax /= 9.0f; cay /= 9.0f; caz /= 9.0f;
        cbx /= 9.0f; cby /= 9.0f; cbz /= 9.0f;

        float H[3][3] = {{0,0,0},{0,0,0},{0,0,0}};
#pragma unroll
        for (int n2 = 0; n2 < 9; ++n2) {
            float a0 = Ax[n2]-cax, a1 = Ay[n2]-cay, a2 = Az[n2]-caz;
            float b0 = Bx[n2]-cbx, b1 = By[n2]-cby, b2 = Bz[n2]-cbz;
            H[0][0]+=a0*b0; H[0][1]+=a0*b1; H[0][2]+=a0*b2;
            H[1][0]+=a1*b0; H[1][1]+=a1*b1; H[1][2]+=a1*b2;
            H[2][0]+=a2*b0; H[2][1]+=a2*b1; H[2][2]+=a2*b2;
        }

        float G[3][3], Vv[3][3];
#pragma unroll
        for (int i = 0; i < 3; ++i)
#pragma unroll
            for (int j = 0; j < 3; ++j) {
                G[i][j]  = H[i][j];
                Vv[i][j] = (i == j) ? 1.0f : 0.0f;
            }
        for (int sw = 0; sw < 12; ++sw) { JROT(0,1); JROT(0,2); JROT(1,2); }

        float s0 = sqrtf(G[0][0]*G[0][0] + G[1][0]*G[1][0] + G[2][0]*G[2][0]);
        float s1 = sqrtf(G[0][1]*G[0][1] + G[1][1]*G[1][1] + G[2][1]*G[2][1]);
        float s2 = sqrtf(G[0][2]*G[0][2] + G[1][2]*G[1][2] + G[2][2]*G[2][2]);
        float r0 = 1.0f / fmaxf(s0, 1e-30f);
        float r1 = 1.0f / fmaxf(s1, 1e-30f);
        float r2 = 1.0f / fmaxf(s2, 1e-30f);
        float U[3][3];
#pragma unroll
        for (int i = 0; i < 3; ++i) {
            U[i][0] = G[i][0] * r0; U[i][1] = G[i][1] * r1; U[i][2] = G[i][2] * r2;
        }
        CSWAP(0, 1); CSWAP(1, 2); CSWAP(0, 1);   // descending singular values

        float R0[3][3];
#pragma unroll
        for (int i = 0; i < 3; ++i)
#pragma unroll
            for (int j = 0; j < 3; ++j)
                R0[i][j] = Vv[i][0]*U[j][0] + Vv[i][1]*U[j][1] + Vv[i][2]*U[j][2];
        float det = R0[0][0]*(R0[1][1]*R0[2][2] - R0[1][2]*R0[2][1])
                  - R0[0][1]*(R0[1][0]*R0[2][2] - R0[1][2]*R0[2][0])
                  + R0[0][2]*(R0[1][0]*R0[2][1] - R0[1][1]*R0[2][0]);
        float dsgn = (det >= 0.0f) ? 1.0f : -1.0f;

        float R[3][3];
#pragma unroll
        for (int i = 0; i < 3; ++i)
#pragma unroll
            for (int j = 0; j < 3; ++j) {
                R[i][j] = Vv[i][0]*U[j][0] + Vv[i][1]*U[j][1] + dsgn*Vv[i][2]*U[j][2];
                out[(size_t)b * 9 + i * 3 + j] = R[i][j];
            }
#pragma unroll
        for (int i = 0; i < 3; ++i) {
            float ti = ((i==0)?cbx:(i==1)?cby:cbz)
                     - (R[i][0]*cax + R[i][1]*cay + R[i][2]*caz);
            out[576 + (size_t)b * 3 + i] = ti;
        }
    }
}

extern "C" void kernel_launch(void* const* d_in, const int* in_sizes, int n_in,
                              void* d_out, int out_size, void* d_ws, size_t ws_size,
                              hipStream_t stream)
{
    const float* pcld = (const float*)d_in[0];
    const float* kpts = (const float*)d_in[1];
    const float* cpt  = (const float*)d_in[2];
    const float* seg  = (const float*)d_in[3];
    const float* mesh = (const float*)d_in[4];
    float* out = (float*)d_out;

    // workspace layout: T[576] f | cnt[576*CSTR] i | pv[576*CAP] f | pi[576*CAP] i
    const size_t tBytes   = (size_t)NB * NCH * sizeof(float);           // 2304
    const size_t cntBytes = (size_t)NB * NCH * CSTR * sizeof(int);      // 36864
    size_t avail = (ws_size > tBytes + cntBytes) ? ws_size - tBytes - cntBytes : 0;
    int CAP = (int)(avail / ((size_t)NB * NCH * 8ull));
    if (CAP > 2048) CAP = 2048;
    if (CAP < 16)   CAP = 16;   // correctness safe via K2 rescan fallback

    float* Tp  = (float*)d_ws;
    int*   cp_ = (int*)((char*)d_ws + tBytes);
    float* pvp = (float*)((char*)d_ws + tBytes + cntBytes);
    int*   pip = (int*)((char*)pvp + (size_t)NB * NCH * CAP * sizeof(float));

    k0_seed<<<NB, 576, 0, stream>>>(kpts, cpt, seg, Tp, cp_);
    k1_gate<<<(NB * NPTS) / 256, 256, 0, stream>>>(kpts, cpt, seg, Tp, pvp, pip, cp_, CAP);
    k2_final<<<NB, 576, 0, stream>>>(pcld, kpts, cpt, seg, mesh, pvp, pip, cp_, out, CAP);
}